// Round 1
// baseline (741.530 us; speedup 1.0000x reference)
//
#include <hip/hip_runtime.h>
#include <hip/hip_bf16.h>

// GCN 2-layer: h1 = relu(GCNConv(x, W1, b1)); out = log_softmax(GCNConv(h1, W2, b2))
// GCNConv(h)[d] = dinv[d] * ( sum_{s->d} (h@W)[s]*dinv[s] + (h@W)[d]*dinv[d] ) + b
//
// Round-11: degree-sorted node permutation for the gather kernels.
// Theory: gathers are latency/issue-bound; waves hold 16 (gather1) / 32
// (gather2) nodes and run neighbor loops to the intra-wave MAX degree
// (Poisson(16): E[max16]~26, E[max32]~28 vs mean 16 -> ~60% lane efficiency).
// Counting-sort nodes into 64 degree bins (counts from bucket_csr's per-node
// degree, one tiny k_perm kernel) and let gather waves process equal-degree
// nodes. All reads/writes stay indexed by real node id -> numerics identical.

#define FEAT_IN 64
#define FEAT_H  32
#define FEAT_O  16
#define MAXNB   512   // max buckets of 256 nodes (n <= 131072; n < 2^24 for packing)
#define PART_G  256   // histogram/partition blocks
#define MAXSNB  128   // max scan blocks for hlen = MAXNB*PART_G
#define DBINS   64    // degree bins for the gather permutation

__device__ __forceinline__ float2 upk_bf2(unsigned w) {
    return make_float2(__uint_as_float(w << 16), __uint_as_float(w & 0xFFFF0000u));
}

// ---- pass 1: per-block bucket histogram -> hist[b*G + g] ----
__global__ void k_hist(const int* __restrict__ dst, int e,
                       int* __restrict__ hist, int G, int NBk,
                       int* __restrict__ dbins) {
    __shared__ int lh[MAXNB];
    int t = threadIdx.x, g = blockIdx.x;
    if (g == 0) {  // zero degree-bin counters (dbins[0:64] counts, [64:128] cursors)
        for (int i = t; i < 2 * DBINS; i += 256) dbins[i] = 0;
    }
    for (int i = t; i < NBk; i += 256) lh[i] = 0;
    __syncthreads();
    int chunk = (e + G - 1) / G;
    int beg = g * chunk, end = min(e, beg + chunk);
    for (int i = beg + t; i < end; i += 256) atomicAdd(&lh[dst[i] >> 8], 1);
    __syncthreads();
    for (int i = t; i < NBk; i += 256) hist[(size_t)i * G + g] = lh[i];
}

// ---- block-local exclusive scan (1024 items/block); bsum[b] = raw block sum ----
__global__ void k_scan1(const int* __restrict__ in, int* __restrict__ out,
                        int* __restrict__ bsum, int len) {
    __shared__ int s[256];
    int t = threadIdx.x;
    int base = blockIdx.x * 1024 + t * 4;
    int a0 = (base + 0) < len ? in[base + 0] : 0;
    int a1 = (base + 1) < len ? in[base + 1] : 0;
    int a2 = (base + 2) < len ? in[base + 2] : 0;
    int a3 = (base + 3) < len ? in[base + 3] : 0;
    int tsum = a0 + a1 + a2 + a3;
    s[t] = tsum;
    __syncthreads();
    for (int off = 1; off < 256; off <<= 1) {
        int x = (t >= off) ? s[t - off] : 0;
        __syncthreads();
        s[t] += x;
        __syncthreads();
    }
    int ex = s[t] - tsum;
    if (base + 0 < len) out[base + 0] = ex;
    if (base + 1 < len) out[base + 1] = ex + a0;
    if (base + 2 < len) out[base + 2] = ex + a0 + a1;
    if (base + 3 < len) out[base + 3] = ex + a0 + a1 + a2;
    if (t == 255) bsum[blockIdx.x] = s[255];
}

// helper run inside consumers: LDS-exclusive-scan of raw bsum[snb] into sps[]
__device__ __forceinline__ void scan_bsum(const int* __restrict__ bsum, int snb,
                                          int* __restrict__ sps, int t) {
    if (t < snb) sps[t] = bsum[t];
    __syncthreads();
    if (t == 0) {
        int acc = 0;
        for (int i = 0; i < snb; ++i) { int v = sps[i]; sps[i] = acc; acc += v; }
    }
    __syncthreads();
}

// ---- pass 2: scatter packed (src | dlow<<24) into bucket-ordered part[] ----
__global__ void k_partition(const int* __restrict__ src, const int* __restrict__ dst, int e,
                            const int* __restrict__ base, const int* __restrict__ bsum,
                            int snb, int* __restrict__ part, int G, int NBk) {
    __shared__ int cur[MAXNB];
    __shared__ int sps[MAXSNB];
    int t = threadIdx.x, g = blockIdx.x;
    scan_bsum(bsum, snb, sps, t);
    for (int i = t; i < NBk; i += 256) {
        size_t idx = (size_t)i * G + g;
        cur[i] = base[idx] + sps[idx >> 10];
    }
    __syncthreads();
    int chunk = (e + G - 1) / G;
    int beg = g * chunk, end = min(e, beg + chunk);
    for (int i = beg + t; i < end; i += 256) {
        int s_ = src[i], d_ = dst[i];
        int pos = atomicAdd(&cur[d_ >> 8], 1);
        part[pos] = s_ | ((d_ & 255) << 24);   // n < 2^24
    }
}

// ---- pass 3: per-bucket CSR: LDS count -> scan -> row_start/dinv -> col fill ----
__global__ void k_bucket_csr(const int* __restrict__ part, const int* __restrict__ base,
                             const int* __restrict__ bsum, int snb, int e, int G, int NBk,
                             int n, int* __restrict__ row_start, int* __restrict__ col,
                             float* __restrict__ dinv, int* __restrict__ dbins) {
    __shared__ int cnt[256], spre[256], cur[256], ssc[256];
    __shared__ int sps[MAXSNB];
    int t = threadIdx.x, b = blockIdx.x;
    scan_bsum(bsum, snb, sps, t);
    size_t ib = (size_t)b * G;
    size_t ie = (size_t)(b + 1) * G;
    int beg = base[ib] + sps[ib >> 10];
    int end = (b == NBk - 1) ? e : (base[ie] + sps[ie >> 10]);
    cnt[t] = 0; cur[t] = 0;
    __syncthreads();
    for (int j = beg + t; j < end; j += 256) atomicAdd(&cnt[((unsigned)part[j]) >> 24], 1);
    __syncthreads();
    int v = cnt[t];
    ssc[t] = v;
    __syncthreads();
    for (int off = 1; off < 256; off <<= 1) {
        int x = (t >= off) ? ssc[t - off] : 0;
        __syncthreads();
        ssc[t] += x;
        __syncthreads();
    }
    spre[t] = ssc[t] - v;  // exclusive prefix within bucket
    int node = b * 256 + t;
    if (node < n) {
        row_start[node] = beg + spre[t];
        dinv[node] = rsqrtf((float)v + 1.0f);  // +1 self-loop
        atomicAdd(&dbins[v < (DBINS - 1) ? v : (DBINS - 1)], 1);  // degree histogram
    }
    if (b == NBk - 1 && t == 0) row_start[n] = e;
    __syncthreads();
    for (int j = beg + t; j < end; j += 256) {
        int r = part[j];
        int dl = ((unsigned)r) >> 24;
        int off = atomicAdd(&cur[dl], 1);
        col[beg + spre[dl] + off] = r & 0x00FFFFFF;
    }
}

// ---- counting-sort nodes by degree -> perm[] (equal-degree nodes adjacent) ----
__global__ void k_perm(const int* __restrict__ row_start, int* __restrict__ dbins,
                       int* __restrict__ perm, int n) {
    __shared__ int sb[DBINS];
    int t = threadIdx.x;
    if (t < DBINS) sb[t] = dbins[t];
    __syncthreads();
    if (t == 0) {  // exclusive scan of 64 bins (every block computes identical copy)
        int acc = 0;
        for (int i = 0; i < DBINS; ++i) { int v = sb[i]; sb[i] = acc; acc += v; }
    }
    __syncthreads();
    int node = blockIdx.x * 256 + t;
    if (node < n) {
        int deg = row_start[node + 1] - row_start[node];
        int bin = deg < (DBINS - 1) ? deg : (DBINS - 1);
        int pos = sb[bin] + atomicAdd(&dbins[DBINS + bin], 1);  // cursors at [64:128]
        perm[pos] = node;
    }
}

// ---- layer 1 GEMM: h1s(bf16) = (x @ W1) * dinv ; 32 nodes/block ----
__global__ void k_gemm1(const float* __restrict__ x, const float* __restrict__ W1,
                        const float* __restrict__ dinv,
                        __hip_bfloat162* __restrict__ h1s2, int n) {
    __shared__ float sW[FEAT_IN * FEAT_H];   // 8 KB
    __shared__ float sx[16][FEAT_IN + 1];
    int t = threadIdx.x;
    for (int i = t; i < FEAT_IN * FEAT_H; i += 256) sW[i] = W1[i];
#pragma unroll
    for (int tile = 0; tile < 2; ++tile) {
        int nodeBase = blockIdx.x * 32 + tile * 16;
        __syncthreads();
        {   // stage 16 nodes of x
            int xn = t >> 4, c = t & 15;
            int node = nodeBase + xn;
            if (node < n) {
                float4 v = ((const float4*)x)[(size_t)node * 16 + c];
                sx[xn][c * 4 + 0] = v.x; sx[xn][c * 4 + 1] = v.y;
                sx[xn][c * 4 + 2] = v.z; sx[xn][c * 4 + 3] = v.w;
            }
        }
        __syncthreads();
        int nl = t >> 4, g = t & 15;
        int node = nodeBase + nl;
        if (node < n) {
            float a0 = 0.0f, a1 = 0.0f;
#pragma unroll
            for (int k = 0; k < FEAT_IN; ++k) {
                float s = sx[nl][k];
                a0 += s * sW[k * FEAT_H + 2 * g];
                a1 += s * sW[k * FEAT_H + 2 * g + 1];
            }
            float dv = dinv[node];
            __hip_bfloat162 o;
            o.x = __float2bfloat16(a0 * dv);
            o.y = __float2bfloat16(a1 * dv);
            h1s2[(size_t)node * 16 + g] = o;
        }
    }
}

// ---- gather layer1 (+relu+bias) fused with GEMM2: 64 nodes x 4 lanes ----
__global__ void k_gather1_gemm2(const int* __restrict__ row_start, const int* __restrict__ col,
                                const uint4* __restrict__ h1q, const float* __restrict__ W2,
                                const float* __restrict__ b1,
                                const float* __restrict__ dinv,
                                const int* __restrict__ perm,
                                __hip_bfloat162* __restrict__ h2s2, int n) {
    __shared__ float sW[FEAT_H * FEAT_O];
    __shared__ float sb1[FEAT_H];
    __shared__ float sz[64][FEAT_H + 1];
    __shared__ int sperm[64];
    int t = threadIdx.x;
    for (int i = t; i < FEAT_H * FEAT_O; i += 256) sW[i] = W2[i];
    if (t < FEAT_H) sb1[t] = b1[t];
    if (t < 64) {
        int idx = blockIdx.x * 64 + t;
        sperm[t] = idx < n ? perm[idx] : -1;
    }
    __syncthreads();

    int g = t >> 2, l = t & 3;          // 64 nodes, 4 lanes each (16B bf16 = 8 feats)
    int d = sperm[g];
    if (d >= 0) {
        float a[8];
        {   // self-loop term
            uint4 u = h1q[(size_t)d * 4 + l];
            float2 p;
            p = upk_bf2(u.x); a[0] = p.x; a[1] = p.y;
            p = upk_bf2(u.y); a[2] = p.x; a[3] = p.y;
            p = upk_bf2(u.z); a[4] = p.x; a[5] = p.y;
            p = upk_bf2(u.w); a[6] = p.x; a[7] = p.y;
        }
        int beg = row_start[d], end = row_start[d + 1];
        int j = beg;
        for (; j + 4 <= end; j += 4) {   // 4 independent 16B gathers in flight
            int c0 = col[j + 0], c1 = col[j + 1], c2 = col[j + 2], c3 = col[j + 3];
            uint4 u0 = h1q[(size_t)c0 * 4 + l];
            uint4 u1 = h1q[(size_t)c1 * 4 + l];
            uint4 u2 = h1q[(size_t)c2 * 4 + l];
            uint4 u3 = h1q[(size_t)c3 * 4 + l];
            float2 p;
            p = upk_bf2(u0.x); a[0] += p.x; a[1] += p.y;
            p = upk_bf2(u0.y); a[2] += p.x; a[3] += p.y;
            p = upk_bf2(u0.z); a[4] += p.x; a[5] += p.y;
            p = upk_bf2(u0.w); a[6] += p.x; a[7] += p.y;
            p = upk_bf2(u1.x); a[0] += p.x; a[1] += p.y;
            p = upk_bf2(u1.y); a[2] += p.x; a[3] += p.y;
            p = upk_bf2(u1.z); a[4] += p.x; a[5] += p.y;
            p = upk_bf2(u1.w); a[6] += p.x; a[7] += p.y;
            p = upk_bf2(u2.x); a[0] += p.x; a[1] += p.y;
            p = upk_bf2(u2.y); a[2] += p.x; a[3] += p.y;
            p = upk_bf2(u2.z); a[4] += p.x; a[5] += p.y;
            p = upk_bf2(u2.w); a[6] += p.x; a[7] += p.y;
            p = upk_bf2(u3.x); a[0] += p.x; a[1] += p.y;
            p = upk_bf2(u3.y); a[2] += p.x; a[3] += p.y;
            p = upk_bf2(u3.z); a[4] += p.x; a[5] += p.y;
            p = upk_bf2(u3.w); a[6] += p.x; a[7] += p.y;
        }
        for (; j < end; ++j) {
            uint4 u = h1q[(size_t)col[j] * 4 + l];
            float2 p;
            p = upk_bf2(u.x); a[0] += p.x; a[1] += p.y;
            p = upk_bf2(u.y); a[2] += p.x; a[3] += p.y;
            p = upk_bf2(u.z); a[4] += p.x; a[5] += p.y;
            p = upk_bf2(u.w); a[6] += p.x; a[7] += p.y;
        }
        float dv = dinv[d];
#pragma unroll
        for (int k = 0; k < 8; ++k)
            sz[g][l * 8 + k] = fmaxf(dv * a[k] + sb1[l * 8 + k], 0.0f);
    }
    __syncthreads();
    // GEMM2: 64 nodes x 8 output-pairs = 512 items / 256 thr = 2 iters; bf16 store
#pragma unroll
    for (int it = 0; it < 2; ++it) {
        int nl = (t >> 3) + it * 32;
        int m = t & 7;
        int node = sperm[nl];
        if (node >= 0) {
            float a0 = 0.0f, a1 = 0.0f;
#pragma unroll
            for (int f = 0; f < FEAT_H; ++f) {
                float z = sz[nl][f];
                a0 += z * sW[f * FEAT_O + 2 * m];
                a1 += z * sW[f * FEAT_O + 2 * m + 1];
            }
            float dv = dinv[node];
            __hip_bfloat162 o;
            o.x = __float2bfloat16(a0 * dv);
            o.y = __float2bfloat16(a1 * dv);
            h2s2[(size_t)node * 8 + m] = o;
        }
    }
}

// ---- gather layer2 + bias + log_softmax: 128 nodes x 2 lanes ----
__global__ void k_gather2_lsm(const int* __restrict__ row_start, const int* __restrict__ col,
                              const uint4* __restrict__ h2q, const float* __restrict__ b2,
                              const float* __restrict__ dinv,
                              const int* __restrict__ perm,
                              float4* __restrict__ out4, int n) {
    __shared__ float sb2[FEAT_O];
    int t = threadIdx.x;
    if (t < FEAT_O) sb2[t] = b2[t];
    __syncthreads();
    int g = t >> 1, h = t & 1;          // 128 nodes, 2 lanes each (16B bf16 = 8 feats)
    int idx = blockIdx.x * 128 + g;
    if (idx >= n) return;
    int d = perm[idx];
    float a[8];
    {
        uint4 u = h2q[(size_t)d * 2 + h];  // self-loop term
        float2 p;
        p = upk_bf2(u.x); a[0] = p.x; a[1] = p.y;
        p = upk_bf2(u.y); a[2] = p.x; a[3] = p.y;
        p = upk_bf2(u.z); a[4] = p.x; a[5] = p.y;
        p = upk_bf2(u.w); a[6] = p.x; a[7] = p.y;
    }
    int beg = row_start[d], end = row_start[d + 1];
    int j = beg;
    for (; j + 4 <= end; j += 4) {
        int c0 = col[j + 0], c1 = col[j + 1], c2 = col[j + 2], c3 = col[j + 3];
        uint4 u0 = h2q[(size_t)c0 * 2 + h];
        uint4 u1 = h2q[(size_t)c1 * 2 + h];
        uint4 u2 = h2q[(size_t)c2 * 2 + h];
        uint4 u3 = h2q[(size_t)c3 * 2 + h];
        float2 p;
        p = upk_bf2(u0.x); a[0] += p.x; a[1] += p.y;
        p = upk_bf2(u0.y); a[2] += p.x; a[3] += p.y;
        p = upk_bf2(u0.z); a[4] += p.x; a[5] += p.y;
        p = upk_bf2(u0.w); a[6] += p.x; a[7] += p.y;
        p = upk_bf2(u1.x); a[0] += p.x; a[1] += p.y;
        p = upk_bf2(u1.y); a[2] += p.x; a[3] += p.y;
        p = upk_bf2(u1.z); a[4] += p.x; a[5] += p.y;
        p = upk_bf2(u1.w); a[6] += p.x; a[7] += p.y;
        p = upk_bf2(u2.x); a[0] += p.x; a[1] += p.y;
        p = upk_bf2(u2.y); a[2] += p.x; a[3] += p.y;
        p = upk_bf2(u2.z); a[4] += p.x; a[5] += p.y;
        p = upk_bf2(u2.w); a[6] += p.x; a[7] += p.y;
        p = upk_bf2(u3.x); a[0] += p.x; a[1] += p.y;
        p = upk_bf2(u3.y); a[2] += p.x; a[3] += p.y;
        p = upk_bf2(u3.z); a[4] += p.x; a[5] += p.y;
        p = upk_bf2(u3.w); a[6] += p.x; a[7] += p.y;
    }
    for (; j < end; ++j) {
        uint4 u = h2q[(size_t)col[j] * 2 + h];
        float2 p;
        p = upk_bf2(u.x); a[0] += p.x; a[1] += p.y;
        p = upk_bf2(u.y); a[2] += p.x; a[3] += p.y;
        p = upk_bf2(u.z); a[4] += p.x; a[5] += p.y;
        p = upk_bf2(u.w); a[6] += p.x; a[7] += p.y;
    }
    float dv = dinv[d];
    float v[8];
    float mx = -1e30f;
#pragma unroll
    for (int k = 0; k < 8; ++k) {
        v[k] = dv * a[k] + sb2[h * 8 + k];
        mx = fmaxf(mx, v[k]);
    }
    mx = fmaxf(mx, __shfl_xor(mx, 1));   // partner lane = same node, other half
    float ssum = 0.0f;
#pragma unroll
    for (int k = 0; k < 8; ++k) ssum += __expf(v[k] - mx);
    ssum += __shfl_xor(ssum, 1);
    float lg = mx + logf(ssum);
    float4 o0 = { v[0] - lg, v[1] - lg, v[2] - lg, v[3] - lg };
    float4 o1 = { v[4] - lg, v[5] - lg, v[6] - lg, v[7] - lg };
    out4[(size_t)d * 4 + h * 2 + 0] = o0;
    out4[(size_t)d * 4 + h * 2 + 1] = o1;
}

extern "C" void kernel_launch(void* const* d_in, const int* in_sizes, int n_in,
                              void* d_out, int out_size, void* d_ws, size_t ws_size,
                              hipStream_t stream) {
    const float* x  = (const float*)d_in[0];
    const int*   ei = (const int*)d_in[1];
    const float* W1 = (const float*)d_in[2];
    const float* b1 = (const float*)d_in[3];
    const float* W2 = (const float*)d_in[4];
    const float* b2 = (const float*)d_in[5];

    const int n = in_sizes[0] / FEAT_IN;   // 100000
    const int e = in_sizes[1] / 2;         // 1600000
    const int* src = ei;
    const int* dst = ei + e;
    const int NBk = (n + 255) >> 8;        // 391 buckets of 256
    const int G = PART_G;                  // 256
    const int hlen = NBk * G;              // 100096
    const int snb = (hlen + 1023) / 1024;  // 98 (<= MAXSNB)

    // workspace; part (4B*e = 6.4MB) aliased with h1s bf16 (32n*2B = 6.4MB):
    // bucket_csr fully consumes part before k_gemm1 writes h1s (stream-ordered)
    int* part = (int*)d_ws;                                   // e ints
    __hip_bfloat162* h1s2 = (__hip_bfloat162*)d_ws;           // 16n bf162, same region
    int* col  = (int*)d_ws + e;                               // e ints
    __hip_bfloat162* h2s2 = (__hip_bfloat162*)(col + e);      // 8n bf162 (3.2MB)
    float* dinv = (float*)(h2s2 + 8 * (size_t)n);             // n
    int* hist      = (int*)(dinv + n);                        // hlen
    int* base      = hist + hlen;                             // hlen
    int* bsum      = base + hlen;                             // snb (raw block sums)
    int* row_start = bsum + MAXSNB;                           // n+1
    int* perm      = row_start + n + 1;                       // n
    int* dbins     = perm + n;                                // 2*DBINS (counts + cursors)

    k_hist<<<G, 256, 0, stream>>>(dst, e, hist, G, NBk, dbins);
    k_scan1<<<snb, 256, 0, stream>>>(hist, base, bsum, hlen);
    k_partition<<<G, 256, 0, stream>>>(src, dst, e, base, bsum, snb, part, G, NBk);
    k_bucket_csr<<<NBk, 256, 0, stream>>>(part, base, bsum, snb, e, G, NBk, n,
                                          row_start, col, dinv, dbins);
    k_perm<<<NBk, 256, 0, stream>>>(row_start, dbins, perm, n);

    k_gemm1<<<(n + 31) / 32, 256, 0, stream>>>(x, W1, dinv, h1s2, n);
    k_gather1_gemm2<<<(n + 63) / 64, 256, 0, stream>>>(row_start, col, (const uint4*)h1s2,
                                                       W2, b1, dinv, perm, h2s2, n);
    k_gather2_lsm<<<(n + 127) / 128, 256, 0, stream>>>(row_start, col, (const uint4*)h2s2,
                                                       b2, dinv, perm, (float4*)d_out, n);
}

// Round 2
// 206.212 us; speedup vs baseline: 3.5960x; 3.5960x over previous
//
#include <hip/hip_runtime.h>
#include <hip/hip_bf16.h>

// GCN 2-layer: h1 = relu(GCNConv(x, W1, b1)); out = log_softmax(GCNConv(h1, W2, b2))
// GCNConv(h)[d] = dinv[d] * ( sum_{s->d} (h@W)[s]*dinv[s] + (h@W)[d]*dinv[d] ) + b
//
// Round-12: r11's degree-sort permutation regressed 4x NOT because of the
// gather change but because of 2x 100K same-address global atomics (dbins
// counts in k_bucket_csr, cursors in k_perm) -> ~500us of L2 atomic
// serialization (VALUBusy 0.26%, HBM 0.5% on k_bucket_csr = pure stall).
// Fix: LDS-aggregate histograms per block, then <=64 global atomics/block
// (k_bucket_csr) and one range-reservation atomic per (block,bin) (k_perm).
// Numerics identical; perm ordering within a bin changes (was nondet anyway).

#define FEAT_IN 64
#define FEAT_H  32
#define FEAT_O  16
#define MAXNB   512   // max buckets of 256 nodes (n <= 131072; n < 2^24 for packing)
#define PART_G  256   // histogram/partition blocks
#define MAXSNB  128   // max scan blocks for hlen = MAXNB*PART_G
#define DBINS   64    // degree bins for the gather permutation

__device__ __forceinline__ float2 upk_bf2(unsigned w) {
    return make_float2(__uint_as_float(w << 16), __uint_as_float(w & 0xFFFF0000u));
}

// ---- pass 1: per-block bucket histogram -> hist[b*G + g] ----
__global__ void k_hist(const int* __restrict__ dst, int e,
                       int* __restrict__ hist, int G, int NBk,
                       int* __restrict__ dbins) {
    __shared__ int lh[MAXNB];
    int t = threadIdx.x, g = blockIdx.x;
    if (g == 0) {  // zero degree-bin counters (dbins[0:64] counts, [64:128] cursors)
        for (int i = t; i < 2 * DBINS; i += 256) dbins[i] = 0;
    }
    for (int i = t; i < NBk; i += 256) lh[i] = 0;
    __syncthreads();
    int chunk = (e + G - 1) / G;
    int beg = g * chunk, end = min(e, beg + chunk);
    for (int i = beg + t; i < end; i += 256) atomicAdd(&lh[dst[i] >> 8], 1);
    __syncthreads();
    for (int i = t; i < NBk; i += 256) hist[(size_t)i * G + g] = lh[i];
}

// ---- block-local exclusive scan (1024 items/block); bsum[b] = raw block sum ----
__global__ void k_scan1(const int* __restrict__ in, int* __restrict__ out,
                        int* __restrict__ bsum, int len) {
    __shared__ int s[256];
    int t = threadIdx.x;
    int base = blockIdx.x * 1024 + t * 4;
    int a0 = (base + 0) < len ? in[base + 0] : 0;
    int a1 = (base + 1) < len ? in[base + 1] : 0;
    int a2 = (base + 2) < len ? in[base + 2] : 0;
    int a3 = (base + 3) < len ? in[base + 3] : 0;
    int tsum = a0 + a1 + a2 + a3;
    s[t] = tsum;
    __syncthreads();
    for (int off = 1; off < 256; off <<= 1) {
        int x = (t >= off) ? s[t - off] : 0;
        __syncthreads();
        s[t] += x;
        __syncthreads();
    }
    int ex = s[t] - tsum;
    if (base + 0 < len) out[base + 0] = ex;
    if (base + 1 < len) out[base + 1] = ex + a0;
    if (base + 2 < len) out[base + 2] = ex + a0 + a1;
    if (base + 3 < len) out[base + 3] = ex + a0 + a1 + a2;
    if (t == 255) bsum[blockIdx.x] = s[255];
}

// helper run inside consumers: LDS-exclusive-scan of raw bsum[snb] into sps[]
__device__ __forceinline__ void scan_bsum(const int* __restrict__ bsum, int snb,
                                          int* __restrict__ sps, int t) {
    if (t < snb) sps[t] = bsum[t];
    __syncthreads();
    if (t == 0) {
        int acc = 0;
        for (int i = 0; i < snb; ++i) { int v = sps[i]; sps[i] = acc; acc += v; }
    }
    __syncthreads();
}

// ---- pass 2: scatter packed (src | dlow<<24) into bucket-ordered part[] ----
__global__ void k_partition(const int* __restrict__ src, const int* __restrict__ dst, int e,
                            const int* __restrict__ base, const int* __restrict__ bsum,
                            int snb, int* __restrict__ part, int G, int NBk) {
    __shared__ int cur[MAXNB];
    __shared__ int sps[MAXSNB];
    int t = threadIdx.x, g = blockIdx.x;
    scan_bsum(bsum, snb, sps, t);
    for (int i = t; i < NBk; i += 256) {
        size_t idx = (size_t)i * G + g;
        cur[i] = base[idx] + sps[idx >> 10];
    }
    __syncthreads();
    int chunk = (e + G - 1) / G;
    int beg = g * chunk, end = min(e, beg + chunk);
    for (int i = beg + t; i < end; i += 256) {
        int s_ = src[i], d_ = dst[i];
        int pos = atomicAdd(&cur[d_ >> 8], 1);
        part[pos] = s_ | ((d_ & 255) << 24);   // n < 2^24
    }
}

// ---- pass 3: per-bucket CSR: LDS count -> scan -> row_start/dinv -> col fill ----
__global__ void k_bucket_csr(const int* __restrict__ part, const int* __restrict__ base,
                             const int* __restrict__ bsum, int snb, int e, int G, int NBk,
                             int n, int* __restrict__ row_start, int* __restrict__ col,
                             float* __restrict__ dinv, int* __restrict__ dbins) {
    __shared__ int cnt[256], spre[256], cur[256], ssc[256];
    __shared__ int sps[MAXSNB];
    __shared__ int dh[DBINS];   // block-local degree histogram
    int t = threadIdx.x, b = blockIdx.x;
    scan_bsum(bsum, snb, sps, t);
    size_t ib = (size_t)b * G;
    size_t ie = (size_t)(b + 1) * G;
    int beg = base[ib] + sps[ib >> 10];
    int end = (b == NBk - 1) ? e : (base[ie] + sps[ie >> 10]);
    cnt[t] = 0; cur[t] = 0;
    if (t < DBINS) dh[t] = 0;
    __syncthreads();
    for (int j = beg + t; j < end; j += 256) atomicAdd(&cnt[((unsigned)part[j]) >> 24], 1);
    __syncthreads();
    int v = cnt[t];
    ssc[t] = v;
    __syncthreads();
    for (int off = 1; off < 256; off <<= 1) {
        int x = (t >= off) ? ssc[t - off] : 0;
        __syncthreads();
        ssc[t] += x;
        __syncthreads();
    }
    spre[t] = ssc[t] - v;  // exclusive prefix within bucket
    int node = b * 256 + t;
    if (node < n) {
        row_start[node] = beg + spre[t];
        dinv[node] = rsqrtf((float)v + 1.0f);  // +1 self-loop
        atomicAdd(&dh[v < (DBINS - 1) ? v : (DBINS - 1)], 1);  // LDS, cheap
    }
    if (b == NBk - 1 && t == 0) row_start[n] = e;
    __syncthreads();
    if (t < DBINS && dh[t] > 0) atomicAdd(&dbins[t], dh[t]);  // <=64 global/block
    for (int j = beg + t; j < end; j += 256) {
        int r = part[j];
        int dl = ((unsigned)r) >> 24;
        int off = atomicAdd(&cur[dl], 1);
        col[beg + spre[dl] + off] = r & 0x00FFFFFF;
    }
}

// ---- counting-sort nodes by degree -> perm[] (equal-degree nodes adjacent) ----
// Contention-free: per-block LDS hist -> one range-reservation atomic per
// (block,bin) -> scatter at sb[bin] + block_base[bin] + local_pos.
__global__ void k_perm(const int* __restrict__ row_start, int* __restrict__ dbins,
                       int* __restrict__ perm, int n) {
    __shared__ int sb[DBINS];     // global exclusive scan of bin counts
    __shared__ int lh[DBINS];     // block-local bin histogram / cursor
    __shared__ int lbase[DBINS];  // block's reserved base within each bin
    int t = threadIdx.x;
    if (t < DBINS) { sb[t] = dbins[t]; lh[t] = 0; }
    __syncthreads();
    if (t == 0) {  // exclusive scan of 64 bins (every block computes identical copy)
        int acc = 0;
        for (int i = 0; i < DBINS; ++i) { int v = sb[i]; sb[i] = acc; acc += v; }
    }
    __syncthreads();
    int node = blockIdx.x * 256 + t;
    int bin = -1, lpos = 0;
    if (node < n) {
        int deg = row_start[node + 1] - row_start[node];
        bin = deg < (DBINS - 1) ? deg : (DBINS - 1);
        lpos = atomicAdd(&lh[bin], 1);            // LDS
    }
    __syncthreads();
    if (t < DBINS && lh[t] > 0)
        lbase[t] = atomicAdd(&dbins[DBINS + t], lh[t]);  // reserve range, global
    __syncthreads();
    if (node < n) perm[sb[bin] + lbase[bin] + lpos] = node;
}

// ---- layer 1 GEMM: h1s(bf16) = (x @ W1) * dinv ; 32 nodes/block ----
__global__ void k_gemm1(const float* __restrict__ x, const float* __restrict__ W1,
                        const float* __restrict__ dinv,
                        __hip_bfloat162* __restrict__ h1s2, int n) {
    __shared__ float sW[FEAT_IN * FEAT_H];   // 8 KB
    __shared__ float sx[16][FEAT_IN + 1];
    int t = threadIdx.x;
    for (int i = t; i < FEAT_IN * FEAT_H; i += 256) sW[i] = W1[i];
#pragma unroll
    for (int tile = 0; tile < 2; ++tile) {
        int nodeBase = blockIdx.x * 32 + tile * 16;
        __syncthreads();
        {   // stage 16 nodes of x
            int xn = t >> 4, c = t & 15;
            int node = nodeBase + xn;
            if (node < n) {
                float4 v = ((const float4*)x)[(size_t)node * 16 + c];
                sx[xn][c * 4 + 0] = v.x; sx[xn][c * 4 + 1] = v.y;
                sx[xn][c * 4 + 2] = v.z; sx[xn][c * 4 + 3] = v.w;
            }
        }
        __syncthreads();
        int nl = t >> 4, g = t & 15;
        int node = nodeBase + nl;
        if (node < n) {
            float a0 = 0.0f, a1 = 0.0f;
#pragma unroll
            for (int k = 0; k < FEAT_IN; ++k) {
                float s = sx[nl][k];
                a0 += s * sW[k * FEAT_H + 2 * g];
                a1 += s * sW[k * FEAT_H + 2 * g + 1];
            }
            float dv = dinv[node];
            __hip_bfloat162 o;
            o.x = __float2bfloat16(a0 * dv);
            o.y = __float2bfloat16(a1 * dv);
            h1s2[(size_t)node * 16 + g] = o;
        }
    }
}

// ---- gather layer1 (+relu+bias) fused with GEMM2: 64 nodes x 4 lanes ----
__global__ void k_gather1_gemm2(const int* __restrict__ row_start, const int* __restrict__ col,
                                const uint4* __restrict__ h1q, const float* __restrict__ W2,
                                const float* __restrict__ b1,
                                const float* __restrict__ dinv,
                                const int* __restrict__ perm,
                                __hip_bfloat162* __restrict__ h2s2, int n) {
    __shared__ float sW[FEAT_H * FEAT_O];
    __shared__ float sb1[FEAT_H];
    __shared__ float sz[64][FEAT_H + 1];
    __shared__ int sperm[64];
    int t = threadIdx.x;
    for (int i = t; i < FEAT_H * FEAT_O; i += 256) sW[i] = W2[i];
    if (t < FEAT_H) sb1[t] = b1[t];
    if (t < 64) {
        int idx = blockIdx.x * 64 + t;
        sperm[t] = idx < n ? perm[idx] : -1;
    }
    __syncthreads();

    int g = t >> 2, l = t & 3;          // 64 nodes, 4 lanes each (16B bf16 = 8 feats)
    int d = sperm[g];
    if (d >= 0) {
        float a[8];
        {   // self-loop term
            uint4 u = h1q[(size_t)d * 4 + l];
            float2 p;
            p = upk_bf2(u.x); a[0] = p.x; a[1] = p.y;
            p = upk_bf2(u.y); a[2] = p.x; a[3] = p.y;
            p = upk_bf2(u.z); a[4] = p.x; a[5] = p.y;
            p = upk_bf2(u.w); a[6] = p.x; a[7] = p.y;
        }
        int beg = row_start[d], end = row_start[d + 1];
        int j = beg;
        for (; j + 4 <= end; j += 4) {   // 4 independent 16B gathers in flight
            int c0 = col[j + 0], c1 = col[j + 1], c2 = col[j + 2], c3 = col[j + 3];
            uint4 u0 = h1q[(size_t)c0 * 4 + l];
            uint4 u1 = h1q[(size_t)c1 * 4 + l];
            uint4 u2 = h1q[(size_t)c2 * 4 + l];
            uint4 u3 = h1q[(size_t)c3 * 4 + l];
            float2 p;
            p = upk_bf2(u0.x); a[0] += p.x; a[1] += p.y;
            p = upk_bf2(u0.y); a[2] += p.x; a[3] += p.y;
            p = upk_bf2(u0.z); a[4] += p.x; a[5] += p.y;
            p = upk_bf2(u0.w); a[6] += p.x; a[7] += p.y;
            p = upk_bf2(u1.x); a[0] += p.x; a[1] += p.y;
            p = upk_bf2(u1.y); a[2] += p.x; a[3] += p.y;
            p = upk_bf2(u1.z); a[4] += p.x; a[5] += p.y;
            p = upk_bf2(u1.w); a[6] += p.x; a[7] += p.y;
            p = upk_bf2(u2.x); a[0] += p.x; a[1] += p.y;
            p = upk_bf2(u2.y); a[2] += p.x; a[3] += p.y;
            p = upk_bf2(u2.z); a[4] += p.x; a[5] += p.y;
            p = upk_bf2(u2.w); a[6] += p.x; a[7] += p.y;
            p = upk_bf2(u3.x); a[0] += p.x; a[1] += p.y;
            p = upk_bf2(u3.y); a[2] += p.x; a[3] += p.y;
            p = upk_bf2(u3.z); a[4] += p.x; a[5] += p.y;
            p = upk_bf2(u3.w); a[6] += p.x; a[7] += p.y;
        }
        for (; j < end; ++j) {
            uint4 u = h1q[(size_t)col[j] * 4 + l];
            float2 p;
            p = upk_bf2(u.x); a[0] += p.x; a[1] += p.y;
            p = upk_bf2(u.y); a[2] += p.x; a[3] += p.y;
            p = upk_bf2(u.z); a[4] += p.x; a[5] += p.y;
            p = upk_bf2(u.w); a[6] += p.x; a[7] += p.y;
        }
        float dv = dinv[d];
#pragma unroll
        for (int k = 0; k < 8; ++k)
            sz[g][l * 8 + k] = fmaxf(dv * a[k] + sb1[l * 8 + k], 0.0f);
    }
    __syncthreads();
    // GEMM2: 64 nodes x 8 output-pairs = 512 items / 256 thr = 2 iters; bf16 store
#pragma unroll
    for (int it = 0; it < 2; ++it) {
        int nl = (t >> 3) + it * 32;
        int m = t & 7;
        int node = sperm[nl];
        if (node >= 0) {
            float a0 = 0.0f, a1 = 0.0f;
#pragma unroll
            for (int f = 0; f < FEAT_H; ++f) {
                float z = sz[nl][f];
                a0 += z * sW[f * FEAT_O + 2 * m];
                a1 += z * sW[f * FEAT_O + 2 * m + 1];
            }
            float dv = dinv[node];
            __hip_bfloat162 o;
            o.x = __float2bfloat16(a0 * dv);
            o.y = __float2bfloat16(a1 * dv);
            h2s2[(size_t)node * 8 + m] = o;
        }
    }
}

// ---- gather layer2 + bias + log_softmax: 128 nodes x 2 lanes ----
__global__ void k_gather2_lsm(const int* __restrict__ row_start, const int* __restrict__ col,
                              const uint4* __restrict__ h2q, const float* __restrict__ b2,
                              const float* __restrict__ dinv,
                              const int* __restrict__ perm,
                              float4* __restrict__ out4, int n) {
    __shared__ float sb2[FEAT_O];
    int t = threadIdx.x;
    if (t < FEAT_O) sb2[t] = b2[t];
    __syncthreads();
    int g = t >> 1, h = t & 1;          // 128 nodes, 2 lanes each (16B bf16 = 8 feats)
    int idx = blockIdx.x * 128 + g;
    if (idx >= n) return;
    int d = perm[idx];
    float a[8];
    {
        uint4 u = h2q[(size_t)d * 2 + h];  // self-loop term
        float2 p;
        p = upk_bf2(u.x); a[0] = p.x; a[1] = p.y;
        p = upk_bf2(u.y); a[2] = p.x; a[3] = p.y;
        p = upk_bf2(u.z); a[4] = p.x; a[5] = p.y;
        p = upk_bf2(u.w); a[6] = p.x; a[7] = p.y;
    }
    int beg = row_start[d], end = row_start[d + 1];
    int j = beg;
    for (; j + 4 <= end; j += 4) {
        int c0 = col[j + 0], c1 = col[j + 1], c2 = col[j + 2], c3 = col[j + 3];
        uint4 u0 = h2q[(size_t)c0 * 2 + h];
        uint4 u1 = h2q[(size_t)c1 * 2 + h];
        uint4 u2 = h2q[(size_t)c2 * 2 + h];
        uint4 u3 = h2q[(size_t)c3 * 2 + h];
        float2 p;
        p = upk_bf2(u0.x); a[0] += p.x; a[1] += p.y;
        p = upk_bf2(u0.y); a[2] += p.x; a[3] += p.y;
        p = upk_bf2(u0.z); a[4] += p.x; a[5] += p.y;
        p = upk_bf2(u0.w); a[6] += p.x; a[7] += p.y;
        p = upk_bf2(u1.x); a[0] += p.x; a[1] += p.y;
        p = upk_bf2(u1.y); a[2] += p.x; a[3] += p.y;
        p = upk_bf2(u1.z); a[4] += p.x; a[5] += p.y;
        p = upk_bf2(u1.w); a[6] += p.x; a[7] += p.y;
        p = upk_bf2(u2.x); a[0] += p.x; a[1] += p.y;
        p = upk_bf2(u2.y); a[2] += p.x; a[3] += p.y;
        p = upk_bf2(u2.z); a[4] += p.x; a[5] += p.y;
        p = upk_bf2(u2.w); a[6] += p.x; a[7] += p.y;
        p = upk_bf2(u3.x); a[0] += p.x; a[1] += p.y;
        p = upk_bf2(u3.y); a[2] += p.x; a[3] += p.y;
        p = upk_bf2(u3.z); a[4] += p.x; a[5] += p.y;
        p = upk_bf2(u3.w); a[6] += p.x; a[7] += p.y;
    }
    for (; j < end; ++j) {
        uint4 u = h2q[(size_t)col[j] * 2 + h];
        float2 p;
        p = upk_bf2(u.x); a[0] += p.x; a[1] += p.y;
        p = upk_bf2(u.y); a[2] += p.x; a[3] += p.y;
        p = upk_bf2(u.z); a[4] += p.x; a[5] += p.y;
        p = upk_bf2(u.w); a[6] += p.x; a[7] += p.y;
    }
    float dv = dinv[d];
    float v[8];
    float mx = -1e30f;
#pragma unroll
    for (int k = 0; k < 8; ++k) {
        v[k] = dv * a[k] + sb2[h * 8 + k];
        mx = fmaxf(mx, v[k]);
    }
    mx = fmaxf(mx, __shfl_xor(mx, 1));   // partner lane = same node, other half
    float ssum = 0.0f;
#pragma unroll
    for (int k = 0; k < 8; ++k) ssum += __expf(v[k] - mx);
    ssum += __shfl_xor(ssum, 1);
    float lg = mx + logf(ssum);
    float4 o0 = { v[0] - lg, v[1] - lg, v[2] - lg, v[3] - lg };
    float4 o1 = { v[4] - lg, v[5] - lg, v[6] - lg, v[7] - lg };
    out4[(size_t)d * 4 + h * 2 + 0] = o0;
    out4[(size_t)d * 4 + h * 2 + 1] = o1;
}

extern "C" void kernel_launch(void* const* d_in, const int* in_sizes, int n_in,
                              void* d_out, int out_size, void* d_ws, size_t ws_size,
                              hipStream_t stream) {
    const float* x  = (const float*)d_in[0];
    const int*   ei = (const int*)d_in[1];
    const float* W1 = (const float*)d_in[2];
    const float* b1 = (const float*)d_in[3];
    const float* W2 = (const float*)d_in[4];
    const float* b2 = (const float*)d_in[5];

    const int n = in_sizes[0] / FEAT_IN;   // 100000
    const int e = in_sizes[1] / 2;         // 1600000
    const int* src = ei;
    const int* dst = ei + e;
    const int NBk = (n + 255) >> 8;        // 391 buckets of 256
    const int G = PART_G;                  // 256
    const int hlen = NBk * G;              // 100096
    const int snb = (hlen + 1023) / 1024;  // 98 (<= MAXSNB)

    // workspace; part (4B*e = 6.4MB) aliased with h1s bf16 (32n*2B = 6.4MB):
    // bucket_csr fully consumes part before k_gemm1 writes h1s (stream-ordered)
    int* part = (int*)d_ws;                                   // e ints
    __hip_bfloat162* h1s2 = (__hip_bfloat162*)d_ws;           // 16n bf162, same region
    int* col  = (int*)d_ws + e;                               // e ints
    __hip_bfloat162* h2s2 = (__hip_bfloat162*)(col + e);      // 8n bf162 (3.2MB)
    float* dinv = (float*)(h2s2 + 8 * (size_t)n);             // n
    int* hist      = (int*)(dinv + n);                        // hlen
    int* base      = hist + hlen;                             // hlen
    int* bsum      = base + hlen;                             // snb (raw block sums)
    int* row_start = bsum + MAXSNB;                           // n+1
    int* perm      = row_start + n + 1;                       // n
    int* dbins     = perm + n;                                // 2*DBINS (counts + cursors)

    k_hist<<<G, 256, 0, stream>>>(dst, e, hist, G, NBk, dbins);
    k_scan1<<<snb, 256, 0, stream>>>(hist, base, bsum, hlen);
    k_partition<<<G, 256, 0, stream>>>(src, dst, e, base, bsum, snb, part, G, NBk);
    k_bucket_csr<<<NBk, 256, 0, stream>>>(part, base, bsum, snb, e, G, NBk, n,
                                          row_start, col, dinv, dbins);
    k_perm<<<NBk, 256, 0, stream>>>(row_start, dbins, perm, n);

    k_gemm1<<<(n + 31) / 32, 256, 0, stream>>>(x, W1, dinv, h1s2, n);
    k_gather1_gemm2<<<(n + 63) / 64, 256, 0, stream>>>(row_start, col, (const uint4*)h1s2,
                                                       W2, b1, dinv, perm, h2s2, n);
    k_gather2_lsm<<<(n + 127) / 128, 256, 0, stream>>>(row_start, col, (const uint4*)h2s2,
                                                       b2, dinv, perm, (float4*)d_out, n);
}

// Round 3
// 197.825 us; speedup vs baseline: 3.7484x; 1.0424x over previous
//
#include <hip/hip_runtime.h>
#include <hip/hip_bf16.h>

// GCN 2-layer: h1 = relu(GCNConv(x, W1, b1)); out = log_softmax(GCNConv(h1, W2, b2))
// GCNConv(h)[d] = dinv[d] * ( sum_{s->d} (h@W)[s]*dinv[s] + (h@W)[d]*dinv[d] ) + b
//
// Round-13: r12 showed GLOBAL degree-sort = +21us net (degree-equal waves won
// something but scattering row_start/col ranges across the whole col array
// lost more, plus k_perm overhead). This round isolates the divergence effect:
// counting-sort nodes by degree WITHIN each 256-node bucket, computed inside
// k_bucket_csr (degree already in LDS; 64-bin counting sort, no global
// atomics, no extra kernel). Gather blocks (64/128 nodes) never straddle a
// bucket -> col reads keep bucket locality; waves get near-equal degrees.

#define FEAT_IN 64
#define FEAT_H  32
#define FEAT_O  16
#define MAXNB   512   // max buckets of 256 nodes (n <= 131072; n < 2^24 for packing)
#define PART_G  256   // histogram/partition blocks
#define MAXSNB  128   // max scan blocks for hlen = MAXNB*PART_G
#define DBINS   64    // degree bins for the in-bucket counting sort

__device__ __forceinline__ float2 upk_bf2(unsigned w) {
    return make_float2(__uint_as_float(w << 16), __uint_as_float(w & 0xFFFF0000u));
}

// ---- pass 1: per-block bucket histogram -> hist[b*G + g] ----
__global__ void k_hist(const int* __restrict__ dst, int e,
                       int* __restrict__ hist, int G, int NBk) {
    __shared__ int lh[MAXNB];
    int t = threadIdx.x, g = blockIdx.x;
    for (int i = t; i < NBk; i += 256) lh[i] = 0;
    __syncthreads();
    int chunk = (e + G - 1) / G;
    int beg = g * chunk, end = min(e, beg + chunk);
    for (int i = beg + t; i < end; i += 256) atomicAdd(&lh[dst[i] >> 8], 1);
    __syncthreads();
    for (int i = t; i < NBk; i += 256) hist[(size_t)i * G + g] = lh[i];
}

// ---- block-local exclusive scan (1024 items/block); bsum[b] = raw block sum ----
__global__ void k_scan1(const int* __restrict__ in, int* __restrict__ out,
                        int* __restrict__ bsum, int len) {
    __shared__ int s[256];
    int t = threadIdx.x;
    int base = blockIdx.x * 1024 + t * 4;
    int a0 = (base + 0) < len ? in[base + 0] : 0;
    int a1 = (base + 1) < len ? in[base + 1] : 0;
    int a2 = (base + 2) < len ? in[base + 2] : 0;
    int a3 = (base + 3) < len ? in[base + 3] : 0;
    int tsum = a0 + a1 + a2 + a3;
    s[t] = tsum;
    __syncthreads();
    for (int off = 1; off < 256; off <<= 1) {
        int x = (t >= off) ? s[t - off] : 0;
        __syncthreads();
        s[t] += x;
        __syncthreads();
    }
    int ex = s[t] - tsum;
    if (base + 0 < len) out[base + 0] = ex;
    if (base + 1 < len) out[base + 1] = ex + a0;
    if (base + 2 < len) out[base + 2] = ex + a0 + a1;
    if (base + 3 < len) out[base + 3] = ex + a0 + a1 + a2;
    if (t == 255) bsum[blockIdx.x] = s[255];
}

// helper run inside consumers: LDS-exclusive-scan of raw bsum[snb] into sps[]
__device__ __forceinline__ void scan_bsum(const int* __restrict__ bsum, int snb,
                                          int* __restrict__ sps, int t) {
    if (t < snb) sps[t] = bsum[t];
    __syncthreads();
    if (t == 0) {
        int acc = 0;
        for (int i = 0; i < snb; ++i) { int v = sps[i]; sps[i] = acc; acc += v; }
    }
    __syncthreads();
}

// ---- pass 2: scatter packed (src | dlow<<24) into bucket-ordered part[] ----
__global__ void k_partition(const int* __restrict__ src, const int* __restrict__ dst, int e,
                            const int* __restrict__ base, const int* __restrict__ bsum,
                            int snb, int* __restrict__ part, int G, int NBk) {
    __shared__ int cur[MAXNB];
    __shared__ int sps[MAXSNB];
    int t = threadIdx.x, g = blockIdx.x;
    scan_bsum(bsum, snb, sps, t);
    for (int i = t; i < NBk; i += 256) {
        size_t idx = (size_t)i * G + g;
        cur[i] = base[idx] + sps[idx >> 10];
    }
    __syncthreads();
    int chunk = (e + G - 1) / G;
    int beg = g * chunk, end = min(e, beg + chunk);
    for (int i = beg + t; i < end; i += 256) {
        int s_ = src[i], d_ = dst[i];
        int pos = atomicAdd(&cur[d_ >> 8], 1);
        part[pos] = s_ | ((d_ & 255) << 24);   // n < 2^24
    }
}

// ---- pass 3: per-bucket CSR + in-bucket degree sort -> perm ----
__global__ void k_bucket_csr(const int* __restrict__ part, const int* __restrict__ base,
                             const int* __restrict__ bsum, int snb, int e, int G, int NBk,
                             int n, int* __restrict__ row_start, int* __restrict__ col,
                             float* __restrict__ dinv, int* __restrict__ perm) {
    __shared__ int cnt[256], spre[256], cur[256], ssc[256];
    __shared__ int sps[MAXSNB];
    __shared__ int dbs[DBINS], dcur[DBINS];
    int t = threadIdx.x, b = blockIdx.x;
    scan_bsum(bsum, snb, sps, t);
    size_t ib = (size_t)b * G;
    size_t ie = (size_t)(b + 1) * G;
    int beg = base[ib] + sps[ib >> 10];
    int end = (b == NBk - 1) ? e : (base[ie] + sps[ie >> 10]);
    cnt[t] = 0; cur[t] = 0;
    if (t < DBINS) { dbs[t] = 0; dcur[t] = 0; }
    __syncthreads();
    for (int j = beg + t; j < end; j += 256) atomicAdd(&cnt[((unsigned)part[j]) >> 24], 1);
    __syncthreads();
    int v = cnt[t];
    ssc[t] = v;
    __syncthreads();
    for (int off = 1; off < 256; off <<= 1) {
        int x = (t >= off) ? ssc[t - off] : 0;
        __syncthreads();
        ssc[t] += x;
        __syncthreads();
    }
    spre[t] = ssc[t] - v;  // exclusive prefix within bucket
    int node = b * 256 + t;
    int bin = -1;
    if (node < n) {
        row_start[node] = beg + spre[t];
        dinv[node] = rsqrtf((float)v + 1.0f);  // +1 self-loop
        bin = v < (DBINS - 1) ? v : (DBINS - 1);
        atomicAdd(&dbs[bin], 1);               // LDS degree histogram
    }
    if (b == NBk - 1 && t == 0) row_start[n] = e;
    __syncthreads();
    if (t == 0) {  // exclusive scan of 64 bins
        int acc = 0;
        for (int i = 0; i < DBINS; ++i) { int q = dbs[i]; dbs[i] = acc; acc += q; }
    }
    __syncthreads();
    if (node < n) {  // in-bucket counting sort: perm slot = bucket base + rank
        int p = atomicAdd(&dcur[bin], 1);
        perm[b * 256 + dbs[bin] + p] = node;
    }
    for (int j = beg + t; j < end; j += 256) {
        int r = part[j];
        int dl = ((unsigned)r) >> 24;
        int off = atomicAdd(&cur[dl], 1);
        col[beg + spre[dl] + off] = r & 0x00FFFFFF;
    }
}

// ---- layer 1 GEMM: h1s(bf16) = (x @ W1) * dinv ; 32 nodes/block ----
__global__ void k_gemm1(const float* __restrict__ x, const float* __restrict__ W1,
                        const float* __restrict__ dinv,
                        __hip_bfloat162* __restrict__ h1s2, int n) {
    __shared__ float sW[FEAT_IN * FEAT_H];   // 8 KB
    __shared__ float sx[16][FEAT_IN + 1];
    int t = threadIdx.x;
    for (int i = t; i < FEAT_IN * FEAT_H; i += 256) sW[i] = W1[i];
#pragma unroll
    for (int tile = 0; tile < 2; ++tile) {
        int nodeBase = blockIdx.x * 32 + tile * 16;
        __syncthreads();
        {   // stage 16 nodes of x
            int xn = t >> 4, c = t & 15;
            int node = nodeBase + xn;
            if (node < n) {
                float4 v = ((const float4*)x)[(size_t)node * 16 + c];
                sx[xn][c * 4 + 0] = v.x; sx[xn][c * 4 + 1] = v.y;
                sx[xn][c * 4 + 2] = v.z; sx[xn][c * 4 + 3] = v.w;
            }
        }
        __syncthreads();
        int nl = t >> 4, g = t & 15;
        int node = nodeBase + nl;
        if (node < n) {
            float a0 = 0.0f, a1 = 0.0f;
#pragma unroll
            for (int k = 0; k < FEAT_IN; ++k) {
                float s = sx[nl][k];
                a0 += s * sW[k * FEAT_H + 2 * g];
                a1 += s * sW[k * FEAT_H + 2 * g + 1];
            }
            float dv = dinv[node];
            __hip_bfloat162 o;
            o.x = __float2bfloat16(a0 * dv);
            o.y = __float2bfloat16(a1 * dv);
            h1s2[(size_t)node * 16 + g] = o;
        }
    }
}

// ---- gather layer1 (+relu+bias) fused with GEMM2: 64 nodes x 4 lanes ----
__global__ void k_gather1_gemm2(const int* __restrict__ row_start, const int* __restrict__ col,
                                const uint4* __restrict__ h1q, const float* __restrict__ W2,
                                const float* __restrict__ b1,
                                const float* __restrict__ dinv,
                                const int* __restrict__ perm,
                                __hip_bfloat162* __restrict__ h2s2, int n) {
    __shared__ float sW[FEAT_H * FEAT_O];
    __shared__ float sb1[FEAT_H];
    __shared__ float sz[64][FEAT_H + 1];
    __shared__ int sperm[64];
    int t = threadIdx.x;
    for (int i = t; i < FEAT_H * FEAT_O; i += 256) sW[i] = W2[i];
    if (t < FEAT_H) sb1[t] = b1[t];
    if (t < 64) {
        int idx = blockIdx.x * 64 + t;
        sperm[t] = idx < n ? perm[idx] : -1;
    }
    __syncthreads();

    int g = t >> 2, l = t & 3;          // 64 nodes, 4 lanes each (16B bf16 = 8 feats)
    int d = sperm[g];
    if (d >= 0) {
        float a[8];
        {   // self-loop term
            uint4 u = h1q[(size_t)d * 4 + l];
            float2 p;
            p = upk_bf2(u.x); a[0] = p.x; a[1] = p.y;
            p = upk_bf2(u.y); a[2] = p.x; a[3] = p.y;
            p = upk_bf2(u.z); a[4] = p.x; a[5] = p.y;
            p = upk_bf2(u.w); a[6] = p.x; a[7] = p.y;
        }
        int beg = row_start[d], end = row_start[d + 1];
        int j = beg;
        for (; j + 4 <= end; j += 4) {   // 4 independent 16B gathers in flight
            int c0 = col[j + 0], c1 = col[j + 1], c2 = col[j + 2], c3 = col[j + 3];
            uint4 u0 = h1q[(size_t)c0 * 4 + l];
            uint4 u1 = h1q[(size_t)c1 * 4 + l];
            uint4 u2 = h1q[(size_t)c2 * 4 + l];
            uint4 u3 = h1q[(size_t)c3 * 4 + l];
            float2 p;
            p = upk_bf2(u0.x); a[0] += p.x; a[1] += p.y;
            p = upk_bf2(u0.y); a[2] += p.x; a[3] += p.y;
            p = upk_bf2(u0.z); a[4] += p.x; a[5] += p.y;
            p = upk_bf2(u0.w); a[6] += p.x; a[7] += p.y;
            p = upk_bf2(u1.x); a[0] += p.x; a[1] += p.y;
            p = upk_bf2(u1.y); a[2] += p.x; a[3] += p.y;
            p = upk_bf2(u1.z); a[4] += p.x; a[5] += p.y;
            p = upk_bf2(u1.w); a[6] += p.x; a[7] += p.y;
            p = upk_bf2(u2.x); a[0] += p.x; a[1] += p.y;
            p = upk_bf2(u2.y); a[2] += p.x; a[3] += p.y;
            p = upk_bf2(u2.z); a[4] += p.x; a[5] += p.y;
            p = upk_bf2(u2.w); a[6] += p.x; a[7] += p.y;
            p = upk_bf2(u3.x); a[0] += p.x; a[1] += p.y;
            p = upk_bf2(u3.y); a[2] += p.x; a[3] += p.y;
            p = upk_bf2(u3.z); a[4] += p.x; a[5] += p.y;
            p = upk_bf2(u3.w); a[6] += p.x; a[7] += p.y;
        }
        for (; j < end; ++j) {
            uint4 u = h1q[(size_t)col[j] * 4 + l];
            float2 p;
            p = upk_bf2(u.x); a[0] += p.x; a[1] += p.y;
            p = upk_bf2(u.y); a[2] += p.x; a[3] += p.y;
            p = upk_bf2(u.z); a[4] += p.x; a[5] += p.y;
            p = upk_bf2(u.w); a[6] += p.x; a[7] += p.y;
        }
        float dv = dinv[d];
#pragma unroll
        for (int k = 0; k < 8; ++k)
            sz[g][l * 8 + k] = fmaxf(dv * a[k] + sb1[l * 8 + k], 0.0f);
    }
    __syncthreads();
    // GEMM2: 64 nodes x 8 output-pairs = 512 items / 256 thr = 2 iters; bf16 store
#pragma unroll
    for (int it = 0; it < 2; ++it) {
        int nl = (t >> 3) + it * 32;
        int m = t & 7;
        int node = sperm[nl];
        if (node >= 0) {
            float a0 = 0.0f, a1 = 0.0f;
#pragma unroll
            for (int f = 0; f < FEAT_H; ++f) {
                float z = sz[nl][f];
                a0 += z * sW[f * FEAT_O + 2 * m];
                a1 += z * sW[f * FEAT_O + 2 * m + 1];
            }
            float dv = dinv[node];
            __hip_bfloat162 o;
            o.x = __float2bfloat16(a0 * dv);
            o.y = __float2bfloat16(a1 * dv);
            h2s2[(size_t)node * 8 + m] = o;
        }
    }
}

// ---- gather layer2 + bias + log_softmax: 128 nodes x 2 lanes ----
__global__ void k_gather2_lsm(const int* __restrict__ row_start, const int* __restrict__ col,
                              const uint4* __restrict__ h2q, const float* __restrict__ b2,
                              const float* __restrict__ dinv,
                              const int* __restrict__ perm,
                              float4* __restrict__ out4, int n) {
    __shared__ float sb2[FEAT_O];
    int t = threadIdx.x;
    if (t < FEAT_O) sb2[t] = b2[t];
    __syncthreads();
    int g = t >> 1, h = t & 1;          // 128 nodes, 2 lanes each (16B bf16 = 8 feats)
    int idx = blockIdx.x * 128 + g;
    if (idx >= n) return;
    int d = perm[idx];
    float a[8];
    {
        uint4 u = h2q[(size_t)d * 2 + h];  // self-loop term
        float2 p;
        p = upk_bf2(u.x); a[0] = p.x; a[1] = p.y;
        p = upk_bf2(u.y); a[2] = p.x; a[3] = p.y;
        p = upk_bf2(u.z); a[4] = p.x; a[5] = p.y;
        p = upk_bf2(u.w); a[6] = p.x; a[7] = p.y;
    }
    int beg = row_start[d], end = row_start[d + 1];
    int j = beg;
    for (; j + 4 <= end; j += 4) {
        int c0 = col[j + 0], c1 = col[j + 1], c2 = col[j + 2], c3 = col[j + 3];
        uint4 u0 = h2q[(size_t)c0 * 2 + h];
        uint4 u1 = h2q[(size_t)c1 * 2 + h];
        uint4 u2 = h2q[(size_t)c2 * 2 + h];
        uint4 u3 = h2q[(size_t)c3 * 2 + h];
        float2 p;
        p = upk_bf2(u0.x); a[0] += p.x; a[1] += p.y;
        p = upk_bf2(u0.y); a[2] += p.x; a[3] += p.y;
        p = upk_bf2(u0.z); a[4] += p.x; a[5] += p.y;
        p = upk_bf2(u0.w); a[6] += p.x; a[7] += p.y;
        p = upk_bf2(u1.x); a[0] += p.x; a[1] += p.y;
        p = upk_bf2(u1.y); a[2] += p.x; a[3] += p.y;
        p = upk_bf2(u1.z); a[4] += p.x; a[5] += p.y;
        p = upk_bf2(u1.w); a[6] += p.x; a[7] += p.y;
        p = upk_bf2(u2.x); a[0] += p.x; a[1] += p.y;
        p = upk_bf2(u2.y); a[2] += p.x; a[3] += p.y;
        p = upk_bf2(u2.z); a[4] += p.x; a[5] += p.y;
        p = upk_bf2(u2.w); a[6] += p.x; a[7] += p.y;
        p = upk_bf2(u3.x); a[0] += p.x; a[1] += p.y;
        p = upk_bf2(u3.y); a[2] += p.x; a[3] += p.y;
        p = upk_bf2(u3.z); a[4] += p.x; a[5] += p.y;
        p = upk_bf2(u3.w); a[6] += p.x; a[7] += p.y;
    }
    for (; j < end; ++j) {
        uint4 u = h2q[(size_t)col[j] * 2 + h];
        float2 p;
        p = upk_bf2(u.x); a[0] += p.x; a[1] += p.y;
        p = upk_bf2(u.y); a[2] += p.x; a[3] += p.y;
        p = upk_bf2(u.z); a[4] += p.x; a[5] += p.y;
        p = upk_bf2(u.w); a[6] += p.x; a[7] += p.y;
    }
    float dv = dinv[d];
    float v[8];
    float mx = -1e30f;
#pragma unroll
    for (int k = 0; k < 8; ++k) {
        v[k] = dv * a[k] + sb2[h * 8 + k];
        mx = fmaxf(mx, v[k]);
    }
    mx = fmaxf(mx, __shfl_xor(mx, 1));   // partner lane = same node, other half
    float ssum = 0.0f;
#pragma unroll
    for (int k = 0; k < 8; ++k) ssum += __expf(v[k] - mx);
    ssum += __shfl_xor(ssum, 1);
    float lg = mx + logf(ssum);
    float4 o0 = { v[0] - lg, v[1] - lg, v[2] - lg, v[3] - lg };
    float4 o1 = { v[4] - lg, v[5] - lg, v[6] - lg, v[7] - lg };
    out4[(size_t)d * 4 + h * 2 + 0] = o0;
    out4[(size_t)d * 4 + h * 2 + 1] = o1;
}

extern "C" void kernel_launch(void* const* d_in, const int* in_sizes, int n_in,
                              void* d_out, int out_size, void* d_ws, size_t ws_size,
                              hipStream_t stream) {
    const float* x  = (const float*)d_in[0];
    const int*   ei = (const int*)d_in[1];
    const float* W1 = (const float*)d_in[2];
    const float* b1 = (const float*)d_in[3];
    const float* W2 = (const float*)d_in[4];
    const float* b2 = (const float*)d_in[5];

    const int n = in_sizes[0] / FEAT_IN;   // 100000
    const int e = in_sizes[1] / 2;         // 1600000
    const int* src = ei;
    const int* dst = ei + e;
    const int NBk = (n + 255) >> 8;        // 391 buckets of 256
    const int G = PART_G;                  // 256
    const int hlen = NBk * G;              // 100096
    const int snb = (hlen + 1023) / 1024;  // 98 (<= MAXSNB)

    // workspace; part (4B*e = 6.4MB) aliased with h1s bf16 (32n*2B = 6.4MB):
    // bucket_csr fully consumes part before k_gemm1 writes h1s (stream-ordered)
    int* part = (int*)d_ws;                                   // e ints
    __hip_bfloat162* h1s2 = (__hip_bfloat162*)d_ws;           // 16n bf162, same region
    int* col  = (int*)d_ws + e;                               // e ints
    __hip_bfloat162* h2s2 = (__hip_bfloat162*)(col + e);      // 8n bf162 (3.2MB)
    float* dinv = (float*)(h2s2 + 8 * (size_t)n);             // n
    int* hist      = (int*)(dinv + n);                        // hlen
    int* base      = hist + hlen;                             // hlen
    int* bsum      = base + hlen;                             // snb (raw block sums)
    int* row_start = bsum + MAXSNB;                           // n+1
    int* perm      = row_start + n + 1;                       // n

    k_hist<<<G, 256, 0, stream>>>(dst, e, hist, G, NBk);
    k_scan1<<<snb, 256, 0, stream>>>(hist, base, bsum, hlen);
    k_partition<<<G, 256, 0, stream>>>(src, dst, e, base, bsum, snb, part, G, NBk);
    k_bucket_csr<<<NBk, 256, 0, stream>>>(part, base, bsum, snb, e, G, NBk, n,
                                          row_start, col, dinv, perm);

    k_gemm1<<<(n + 31) / 32, 256, 0, stream>>>(x, W1, dinv, h1s2, n);
    k_gather1_gemm2<<<(n + 63) / 64, 256, 0, stream>>>(row_start, col, (const uint4*)h1s2,
                                                       W2, b1, dinv, perm, h2s2, n);
    k_gather2_lsm<<<(n + 127) / 128, 256, 0, stream>>>(row_start, col, (const uint4*)h2s2,
                                                       b2, dinv, perm, (float4*)d_out, n);
}